// Round 4
// baseline (109.650 us; speedup 1.0000x reference)
//
#include <hip/hip_runtime.h>
#include <math.h>

#define N_OCT  16
#define NS     32768
#define TPB    256
#define NSPLIT 4                  // chunks per row
#define CHUNK  (NS / NSPLIT)      // 8192 samples per block
#define SPT    (CHUNK / TPB)      // 32 samples per thread
#define N_BE   512                // B*E = 8*64

typedef float v2f __attribute__((ext_vector_type(2)));

static __device__ __forceinline__ v2f fma2(v2f a, v2f b, v2f c) {
    return __builtin_elementwise_fma(a, b, c);
}

// R4 structure. R3 counters: dur 44.6us but VALU issue only ~16us GPU-avg and
// Occupancy 21% -> stall/IMBALANCE-bound (1 block per row, 2 blocks/CU, per-row
// work varies 8x with live-octave count; slowest CU = two NP=8 rows). Fix:
// decouple rows from blocks. Each row is split into NSPLIT=4 sample chunks
// handled by independent blocks (2048 blocks x 256 thr = 8192 waves = 100% of
// wave slots; consecutive bids round-robin CUs -> each CU averages 8
// independent row-draws -> max/mean ~1.3 instead of ~2.7). Row-wide max can't
// live in one block, so two dispatches:
//   K1: recurrence over chunk, max only, write ws[row*4+q] (2048 private
//       slots, no atomics, every slot written -> poison-proof).
//   K2: recompute constants+seeds at chunk offset (recurrence is O(1)
//       seedable anywhere via sin), norm = 1/(max of 4 slots + eps) folded
//       into the seed (linear recurrence), store normalized fp32 coalesced.
// Recurrence step is now TPB=256: c2 = 2cos(256*theta) as double-float pair
// (unchanged scheme, 2^-48 effective frequency error).
// Dead-octave skip retained: nyquist cut zeroes a SUFFIX (f0s non-decreasing
// in octave); template<NP> dispatch keeps all array indexing static.

// ---- shared prologue: lanes t<16 compute per-octave block-uniform consts ----
static __device__ __forceinline__ void make_consts(
    int be, int t,
    const float* __restrict__ f0_in, const float* __restrict__ dc_in,
    const float* __restrict__ fs_in,
    double* __restrict__ sR, float* __restrict__ sCH,
    float* __restrict__ sCL, float* __restrict__ sAMP, int* __restrict__ sLive)
{
    if (t < N_OCT) {
        const int o = t;
        const float f0a = fabsf(f0_in[be]);
        const float dc  = dc_in[be];
        const float fs  = fs_in[be];

        const float MINF = (float)(20.0 / 11025.0);
        const float FRNG = (float)(3000.0 / 11025.0 - 20.0 / 11025.0);

        // double sigmoid (reference applies sigmoid twice), decay ladder
        const float s1    = 1.0f / (1.0f + __expf(-dc));
        const float dv    = 1.0f / (1.0f + __expf(-s1));
        const float decay = 0.01f + dv * 0.9801f;          // (1-0.01)*0.99
        const float logd  = __logf(decay + 1e-12f);
        const float f0r   = (MINF + f0a * FRNG) * 3.14159274101257324f;

        // sequential float cumsum, bit-matching the reference's jnp.cumsum
        float cl = 0.f, cf = 0.f;
        for (int i = 0; i <= o; ++i) { cl += logd; cf += fs; }
        float ed  = __expf(cl);                            // decay^(o+1)
        float f0s = f0r * cf;                              // rad/sample
        float a   = ed;
        const bool live = (f0s < 1.0f);                    // nyquist cutoff
        if (!live) { a = 0.0f; f0s = 0.0f; }

        unsigned long long lm = __ballot(live);
        if (o == 0) *sLive = __popcll(lm);

        const double inv2pi = 0.15915494309189535;
        double r = (double)f0s * inv2pi;                   // revolutions/sample

        // c2 = 2*cos(TPB*theta) as double-float pair (single-float c2 is
        // ill-conditioned when TPB*theta mod 2pi ~ 0/pi)
        double drev = r * (double)TPB;
        drev -= floor(drev);
        double c2d = 2.0 * cos(drev * 6.283185307179586);
        float  ch  = (float)c2d;

        sR[o]   = r;
        sCH[o]  = ch;
        sCL[o]  = (float)(c2d - (double)ch);
        sAMP[o] = a;
    }
}

// seed oscillator pair state at sample offset base: y[s] = amp*sin((s+1)*th)
template<int NP>
static __device__ __forceinline__ void seed_state(
    int base, int t,
    const double* __restrict__ sR, const float* __restrict__ sCH,
    const float* __restrict__ sCL, const float* __restrict__ sAMP,
    v2f* xp, v2f* xc, v2f* c2h, v2f* c2l)
{
    #pragma unroll
    for (int o = 0; o < 2 * NP; ++o) {
        const double r = sR[o];
        const float  a = sAMP[o];                      // 0 for dead octaves
        double p0 = r * (double)(base + t + 1);
        p0 -= floor(p0);
        double pm = r * (double)(base + t + 1 - TPB);
        pm -= floor(pm);
        float xcur  = a * __builtin_amdgcn_sinf((float)p0);   // amp folded in
        float xprev = a * __builtin_amdgcn_sinf((float)pm);
        const int j = o >> 1;
        if ((o & 1) == 0) {
            xc[j].x = xcur;    xp[j].x = xprev;
            c2h[j].x = sCH[o]; c2l[j].x = sCL[o];
        } else {
            xc[j].y = xcur;    xp[j].y = xprev;
            c2h[j].y = sCH[o]; c2l[j].y = sCL[o];
        }
    }
}

// ---- K1 body: max over chunk only ----
template<int NP>
static __device__ __forceinline__ void body_max(
    int base, int t,
    const double* __restrict__ sR, const float* __restrict__ sCH,
    const float* __restrict__ sCL, const float* __restrict__ sAMP,
    float* __restrict__ wmax, float* __restrict__ slot)
{
    v2f xp[NP], xc[NP], c2h[NP], c2l[NP];
    seed_state<NP>(base, t, sR, sCH, sCL, sAMP, xp, xc, c2h, c2l);

    float lmax = 0.0f;
    #pragma unroll 4
    for (int k = 0; k < SPT; ++k) {
        v2f acc2 = (v2f)(0.0f);
        #pragma unroll
        for (int j = 0; j < NP; ++j) {
            acc2 += xc[j];
            v2f xn = fma2(c2h[j], xc[j], fma2(c2l[j], xc[j], -xp[j]));
            xp[j] = xc[j];
            xc[j] = xn;
        }
        lmax = fmaxf(lmax, fabsf(acc2.x + acc2.y));
    }

    #pragma unroll
    for (int off = 32; off > 0; off >>= 1)
        lmax = fmaxf(lmax, __shfl_down(lmax, off, 64));
    if ((t & 63) == 0) wmax[t >> 6] = lmax;
    __syncthreads();
    if (t == 0) {
        float bmax = wmax[0];
        #pragma unroll
        for (int w = 1; w < TPB / 64; ++w) bmax = fmaxf(bmax, wmax[w]);
        *slot = bmax;
    }
}

// ---- K2 body: recompute with norm folded into seed, store ----
template<int NP>
static __device__ __forceinline__ void body_store(
    int base, int t, float norm,
    const double* __restrict__ sR, const float* __restrict__ sCH,
    const float* __restrict__ sCL, const float* __restrict__ sAMP,
    float* __restrict__ ochunk)
{
    v2f xp[NP], xc[NP], c2h[NP], c2l[NP];
    seed_state<NP>(base, t, sR, sCH, sCL, sAMP, xp, xc, c2h, c2l);
    #pragma unroll
    for (int j = 0; j < NP; ++j) { xc[j] *= norm; xp[j] *= norm; }

    #pragma unroll 4
    for (int k = 0; k < SPT; ++k) {
        v2f acc2 = (v2f)(0.0f);
        #pragma unroll
        for (int j = 0; j < NP; ++j) {
            acc2 += xc[j];
            v2f xn = fma2(c2h[j], xc[j], fma2(c2l[j], xc[j], -xp[j]));
            xp[j] = xc[j];
            xc[j] = xn;
        }
        ochunk[k * TPB + t] = acc2.x + acc2.y;         // coalesced dword store
    }
}

__global__ __launch_bounds__(TPB, 1)
void f0res_max(const float* __restrict__ f0_in,
               const float* __restrict__ dc_in,
               const float* __restrict__ fs_in,
               float* __restrict__ ws)
{
    __shared__ double sR[N_OCT];
    __shared__ float  sCH[N_OCT], sCL[N_OCT], sAMP[N_OCT];
    __shared__ float  wmax[TPB / 64];
    __shared__ int    sLive;

    const int bid = blockIdx.x;
    const int be  = bid >> 2;                          // row
    const int q   = bid & 3;                           // chunk
    const int t   = threadIdx.x;
    const int base = q * CHUNK;

    make_consts(be, t, f0_in, dc_in, fs_in, sR, sCH, sCL, sAMP, &sLive);
    __syncthreads();

    const int NP = (sLive + 1) >> 1;
    float* slot = ws + bid;                            // private, always written

    switch (NP) {
    case 0: if (t == 0) *slot = 0.0f; break;
    case 1: body_max<1>(base, t, sR, sCH, sCL, sAMP, wmax, slot); break;
    case 2: body_max<2>(base, t, sR, sCH, sCL, sAMP, wmax, slot); break;
    case 3: body_max<3>(base, t, sR, sCH, sCL, sAMP, wmax, slot); break;
    case 4: body_max<4>(base, t, sR, sCH, sCL, sAMP, wmax, slot); break;
    case 5: body_max<5>(base, t, sR, sCH, sCL, sAMP, wmax, slot); break;
    case 6: body_max<6>(base, t, sR, sCH, sCL, sAMP, wmax, slot); break;
    case 7: body_max<7>(base, t, sR, sCH, sCL, sAMP, wmax, slot); break;
    default: body_max<8>(base, t, sR, sCH, sCL, sAMP, wmax, slot); break;
    }
}

__global__ __launch_bounds__(TPB, 1)
void f0res_store(const float* __restrict__ f0_in,
                 const float* __restrict__ dc_in,
                 const float* __restrict__ fs_in,
                 const float* __restrict__ ws,
                 float* __restrict__ out)
{
    __shared__ double sR[N_OCT];
    __shared__ float  sCH[N_OCT], sCL[N_OCT], sAMP[N_OCT];
    __shared__ int    sLive;

    const int bid = blockIdx.x;
    const int be  = bid >> 2;
    const int q   = bid & 3;
    const int t   = threadIdx.x;
    const int base = q * CHUNK;

    make_consts(be, t, f0_in, dc_in, fs_in, sR, sCH, sCL, sAMP, &sLive);
    __syncthreads();

    // row max across the 4 chunk slots (uniform -> scalar loads)
    const int r4 = be << 2;
    const float bmax = fmaxf(fmaxf(ws[r4 + 0], ws[r4 + 1]),
                             fmaxf(ws[r4 + 2], ws[r4 + 3]));
    const float norm = 1.0f / (bmax + 1e-8f);

    const int NP = (sLive + 1) >> 1;
    float* __restrict__ ochunk = out + (size_t)be * NS + base;

    switch (NP) {
    case 0: {
        #pragma unroll
        for (int k = 0; k < SPT; ++k) ochunk[k * TPB + t] = 0.0f;
        break;
    }
    case 1: body_store<1>(base, t, norm, sR, sCH, sCL, sAMP, ochunk); break;
    case 2: body_store<2>(base, t, norm, sR, sCH, sCL, sAMP, ochunk); break;
    case 3: body_store<3>(base, t, norm, sR, sCH, sCL, sAMP, ochunk); break;
    case 4: body_store<4>(base, t, norm, sR, sCH, sCL, sAMP, ochunk); break;
    case 5: body_store<5>(base, t, norm, sR, sCH, sCL, sAMP, ochunk); break;
    case 6: body_store<6>(base, t, norm, sR, sCH, sCL, sAMP, ochunk); break;
    case 7: body_store<7>(base, t, norm, sR, sCH, sCL, sAMP, ochunk); break;
    default: body_store<8>(base, t, norm, sR, sCH, sCL, sAMP, ochunk); break;
    }
}

extern "C" void kernel_launch(void* const* d_in, const int* in_sizes, int n_in,
                              void* d_out, int out_size, void* d_ws, size_t ws_size,
                              hipStream_t stream) {
    const float* f0 = (const float*)d_in[0];
    const float* dc = (const float*)d_in[1];
    const float* fs = (const float*)d_in[3];   // d_in[2] is "unused"
    float* out = (float*)d_out;
    float* ws  = (float*)d_ws;                 // 2048 floats of per-chunk maxes

    hipLaunchKernelGGL(f0res_max, dim3(N_BE * NSPLIT), dim3(TPB),
                       0, stream, f0, dc, fs, ws);
    hipLaunchKernelGGL(f0res_store, dim3(N_BE * NSPLIT), dim3(TPB),
                       0, stream, f0, dc, fs, ws, out);
}